// Round 1
// baseline (361.044 us; speedup 1.0000x reference)
//
#include <hip/hip_runtime.h>

// ---------------------------------------------------------------------------
// TabularDiffFlow sparse-attention pipeline, MI355X (gfx950)
// B=64, N=256, D=512, H=8, HD=64, top-k = 128 of 256 per score row.
//
// Precision plan: q,k projections and QK^T in split-bf16 (hi+lo, 3 MFMAs)
// so top-k boundary decisions match the fp32 reference; v/P/out-proj plain bf16.
// ---------------------------------------------------------------------------

typedef __attribute__((ext_vector_type(8))) short short8;
typedef __attribute__((ext_vector_type(4))) float float4v;

#define MFMA16(A,B,C) __builtin_amdgcn_mfma_f32_16x16x32_bf16((A),(B),(C),0,0,0)

__device__ __forceinline__ ushort f2bf(float f){
  unsigned u = __float_as_uint(f);
  unsigned r = u + 0x7FFFu + ((u >> 16) & 1u);   // round-to-nearest-even
  return (ushort)(r >> 16);
}
__device__ __forceinline__ float bf2f(ushort h){
  return __uint_as_float(((unsigned)h) << 16);
}
// inverse of the "sortable uint" map (monotone uint <-> float bits)
__device__ __forceinline__ float unsort_u(unsigned u){
  unsigned b = (u & 0x80000000u) ? (u ^ 0x80000000u) : ~u;
  return __uint_as_float(b);
}

// ---------------------------------------------------------------- cvt_x ----
__global__ __launch_bounds__(256) void cvt_x_k(const float* __restrict__ x,
                                               ushort* __restrict__ xhi,
                                               ushort* __restrict__ xlo){
  size_t i = ((size_t)blockIdx.x * 256 + threadIdx.x) * 8;
  float4v a = *(const float4v*)(x + i);
  float4v b = *(const float4v*)(x + i + 4);
  float v0=a[0],v1=a[1],v2=a[2],v3=a[3],v4=b[0],v5=b[1],v6=b[2],v7=b[3];
  ushort h0=f2bf(v0),h1=f2bf(v1),h2=f2bf(v2),h3=f2bf(v3);
  ushort h4=f2bf(v4),h5=f2bf(v5),h6=f2bf(v6),h7=f2bf(v7);
  ushort l0=f2bf(v0-bf2f(h0)),l1=f2bf(v1-bf2f(h1)),l2=f2bf(v2-bf2f(h2)),l3=f2bf(v3-bf2f(h3));
  ushort l4=f2bf(v4-bf2f(h4)),l5=f2bf(v5-bf2f(h5)),l6=f2bf(v6-bf2f(h6)),l7=f2bf(v7-bf2f(h7));
  uint4 ph, pl;
  ph.x = h0 | ((unsigned)h1<<16); ph.y = h2 | ((unsigned)h3<<16);
  ph.z = h4 | ((unsigned)h5<<16); ph.w = h6 | ((unsigned)h7<<16);
  pl.x = l0 | ((unsigned)l1<<16); pl.y = l2 | ((unsigned)l3<<16);
  pl.z = l4 | ((unsigned)l5<<16); pl.w = l6 | ((unsigned)l7<<16);
  *(uint4*)(xhi + i) = ph;
  *(uint4*)(xlo + i) = pl;
}

// ---------------------------------------------------------------- cvt_w ----
// Wthi/Wtlo: [1536][512] transposed (out-major) bf16 hi/lo (lo only for q,k rows)
// Wot: [512][512] transposed bf16.  fb: fused bias [1536] fp32.
__global__ __launch_bounds__(256) void cvt_w_k(
    const float* __restrict__ Wq, const float* __restrict__ Wk,
    const float* __restrict__ Wv, const float* __restrict__ Wo,
    const float* __restrict__ bq, const float* __restrict__ bk, const float* __restrict__ bv,
    ushort* __restrict__ Wthi, ushort* __restrict__ Wtlo, ushort* __restrict__ Wot,
    float* __restrict__ fb){
  int r = blockIdx.x, t = threadIdx.x;
  if (r < 1536) {
    const float* W = (r < 512) ? Wq : ((r < 1024) ? Wk : Wv);
    int o = r & 511;
    bool dolo = (r < 1024);
    for (int i = t; i < 512; i += 256) {
      float f = W[(size_t)i*512 + o];
      ushort hi = f2bf(f);
      Wthi[(size_t)r*512 + i] = hi;
      if (dolo) Wtlo[(size_t)r*512 + i] = f2bf(f - bf2f(hi));
    }
  } else if (r < 2048) {
    int o = r - 1536;
    for (int i = t; i < 512; i += 256)
      Wot[(size_t)o*512 + i] = f2bf(Wo[(size_t)i*512 + o]);
  } else {
    for (int i = t; i < 1536; i += 256)
      fb[i] = (i < 512) ? bq[i] : ((i < 1024) ? bk[i-512] : bv[i-1024]);
  }
}

// ------------------------------------------------------------ prior_eff ----
__global__ __launch_bounds__(256) void prior_k(const float* __restrict__ prior,
    const float* __restrict__ fimp, float* __restrict__ pe){
  int i = blockIdx.x, j = threadIdx.x;
  pe[(size_t)i*256 + j] = prior[(size_t)i*256 + j] * fimp[i] * fimp[j];
}

// -------------------------------------------------------------- pv path ----
__global__ __launch_bounds__(256) void pv_mean_k(const float* __restrict__ x,
                                                 float* __restrict__ comb){
  int b = blockIdx.x, t = threadIdx.x;
  const float* xb = x + (size_t)b * 131072;   // 256*512
  float p0=0.f,p1=0.f,q0=0.f,q1=0.f;
  for (int n = 0; n < 128; n++){ p0 += xb[n*512 + t]; p1 += xb[n*512 + t + 256]; }
  for (int n = 128; n < 256; n++){ q0 += xb[n*512 + t]; q1 += xb[n*512 + t + 256]; }
  const float s = 1.0f/128.0f;
  comb[(size_t)b*1024 + t]         = p0*s;
  comb[(size_t)b*1024 + t + 256]   = p1*s;
  comb[(size_t)b*1024 + 512 + t]       = q0*s;
  comb[(size_t)b*1024 + 512 + t + 256] = q1*s;
}

__global__ __launch_bounds__(256) void pv_mlp_k(const float* __restrict__ comb,
    const float* __restrict__ W1, const float* __restrict__ b1,
    const float* __restrict__ W2, const float* __restrict__ b2,
    float* __restrict__ pvc){
  __shared__ float cs[1024];
  __shared__ float red[256];
  int b = blockIdx.x, t = threadIdx.x;
  for (int i = t; i < 1024; i += 256) cs[i] = comb[(size_t)b*1024 + i];
  __syncthreads();
  float a0 = b1[t], a1 = b1[t + 256];
  for (int i = 0; i < 1024; i++){
    float c = cs[i];
    a0 = fmaf(c, W1[(size_t)i*512 + t],       a0);
    a1 = fmaf(c, W1[(size_t)i*512 + t + 256], a1);
  }
  float h0 = a0 / (1.0f + __expf(-a0));   // silu
  float h1 = a1 / (1.0f + __expf(-a1));
  red[t] = fmaf(h0, W2[t], h1 * W2[t + 256]);
  __syncthreads();
  for (int s = 128; s > 0; s >>= 1){
    if (t < s) red[t] += red[t + s];
    __syncthreads();
  }
  if (t == 0) pvc[b] = 1.0f / (1.0f + __expf(-(red[0] + b2[0])));
}

// ------------------------------------------------ split GEMM for q and k ---
// C = (Ahi+Alo) @ (Bhi+Blo)^T(stored row-major by out-col) + bias, 3-MFMA split.
// Output: bf16 hi/lo pairs in [B,H,N,HD] head layout.
__global__ __launch_bounds__(256) void gemm_qk(
    const ushort* __restrict__ Ahi, const ushort* __restrict__ Alo,
    const ushort* __restrict__ Bhi, const ushort* __restrict__ Blo,
    const float* __restrict__ bias,
    ushort* __restrict__ qhi, ushort* __restrict__ qlo,
    ushort* __restrict__ khi, ushort* __restrict__ klo)
{
  __shared__ __align__(16) ushort As[2][128][40];
  __shared__ __align__(16) ushort Bs[2][128][40];
  int n0 = blockIdx.x * 128, m0 = blockIdx.y * 128;
  int tid = threadIdx.x, lane = tid & 63, w = tid >> 6, wm = w >> 1, wn = w & 1;
  float4v acc[4][4] = {};
  for (int k0 = 0; k0 < 512; k0 += 32){
    for (int c = tid; c < 512; c += 256){
      int row = c >> 2, ch = c & 3;
      *(uint4*)(&As[0][row][ch*8]) = *(const uint4*)(Ahi + (size_t)(m0+row)*512 + k0 + ch*8);
      *(uint4*)(&As[1][row][ch*8]) = *(const uint4*)(Alo + (size_t)(m0+row)*512 + k0 + ch*8);
      *(uint4*)(&Bs[0][row][ch*8]) = *(const uint4*)(Bhi + (size_t)(n0+row)*512 + k0 + ch*8);
      *(uint4*)(&Bs[1][row][ch*8]) = *(const uint4*)(Blo + (size_t)(n0+row)*512 + k0 + ch*8);
    }
    __syncthreads();
    short8 ah[4], al[4], bh[4], bl[4];
    #pragma unroll
    for (int i = 0; i < 4; i++){
      ah[i] = *(const short8*)(&As[0][wm*64 + i*16 + (lane&15)][(lane>>4)*8]);
      al[i] = *(const short8*)(&As[1][wm*64 + i*16 + (lane&15)][(lane>>4)*8]);
      bh[i] = *(const short8*)(&Bs[0][wn*64 + i*16 + (lane&15)][(lane>>4)*8]);
      bl[i] = *(const short8*)(&Bs[1][wn*64 + i*16 + (lane&15)][(lane>>4)*8]);
    }
    #pragma unroll
    for (int mi = 0; mi < 4; mi++){
      #pragma unroll
      for (int ni = 0; ni < 4; ni++){
        acc[mi][ni] = MFMA16(ah[mi], bh[ni], acc[mi][ni]);
        acc[mi][ni] = MFMA16(ah[mi], bl[ni], acc[mi][ni]);
        acc[mi][ni] = MFMA16(al[mi], bh[ni], acc[mi][ni]);
      }
    }
    __syncthreads();
  }
  #pragma unroll
  for (int mi = 0; mi < 4; mi++){
    #pragma unroll
    for (int ni = 0; ni < 4; ni++){
      #pragma unroll
      for (int r = 0; r < 4; r++){
        int rg = m0 + wm*64 + mi*16 + ((lane>>4)<<2) + r;
        int cg = n0 + wn*64 + ni*16 + (lane&15);
        float val = acc[mi][ni][r] + bias[cg];
        int which = cg >> 9, within = cg & 511;
        int bb = rg >> 8, seq = rg & 255, hh = within >> 6, hd = within & 63;
        size_t idx = ((size_t)((bb*8 + hh)*256 + seq))*64 + hd;
        ushort hi_ = f2bf(val);
        ushort lo_ = f2bf(val - bf2f(hi_));
        if (which == 0) { qhi[idx] = hi_; qlo[idx] = lo_; }
        else            { khi[idx] = hi_; klo[idx] = lo_; }
      }
    }
  }
}

// ------------------------------------------- plain bf16 GEMM (v, out-proj) -
// EPI=0: out = bf16 [B,H,N,HD] head layout (v).  EPI=1: out = fp32 [M][512].
template<int EPI>
__global__ __launch_bounds__(256) void gemm_pl(
    const ushort* __restrict__ A, const ushort* __restrict__ Bt,
    const float* __restrict__ bias, void* __restrict__ outp)
{
  __shared__ __align__(16) ushort As[128][40];
  __shared__ __align__(16) ushort Bs[128][40];
  int n0 = blockIdx.x * 128, m0 = blockIdx.y * 128;
  int tid = threadIdx.x, lane = tid & 63, w = tid >> 6, wm = w >> 1, wn = w & 1;
  float4v acc[4][4] = {};
  for (int k0 = 0; k0 < 512; k0 += 32){
    for (int c = tid; c < 512; c += 256){
      int row = c >> 2, ch = c & 3;
      *(uint4*)(&As[row][ch*8]) = *(const uint4*)(A  + (size_t)(m0+row)*512 + k0 + ch*8);
      *(uint4*)(&Bs[row][ch*8]) = *(const uint4*)(Bt + (size_t)(n0+row)*512 + k0 + ch*8);
    }
    __syncthreads();
    short8 af[4], bg[4];
    #pragma unroll
    for (int i = 0; i < 4; i++){
      af[i] = *(const short8*)(&As[wm*64 + i*16 + (lane&15)][(lane>>4)*8]);
      bg[i] = *(const short8*)(&Bs[wn*64 + i*16 + (lane&15)][(lane>>4)*8]);
    }
    #pragma unroll
    for (int mi = 0; mi < 4; mi++){
      #pragma unroll
      for (int ni = 0; ni < 4; ni++)
        acc[mi][ni] = MFMA16(af[mi], bg[ni], acc[mi][ni]);
    }
    __syncthreads();
  }
  #pragma unroll
  for (int mi = 0; mi < 4; mi++){
    #pragma unroll
    for (int ni = 0; ni < 4; ni++){
      #pragma unroll
      for (int r = 0; r < 4; r++){
        int rg = m0 + wm*64 + mi*16 + ((lane>>4)<<2) + r;
        int cg = n0 + wn*64 + ni*16 + (lane&15);
        float val = acc[mi][ni][r] + bias[cg];
        if (EPI == 0){
          int bb = rg >> 8, seq = rg & 255, hh = cg >> 6, hd = cg & 63;
          ((ushort*)outp)[((size_t)((bb*8 + hh)*256 + seq))*64 + hd] = f2bf(val);
        } else {
          ((float*)outp)[(size_t)rg*512 + cg] = val;
        }
      }
    }
  }
}

// ------------------------------------------------------ fused attention ----
// One block per (b,h). 4 waves; wave w owns q rows [w*64, w*64+64) in 4 tiles
// of 16. Swapped QK^T: mfma(K,Q) => lane holds the full 256-score row of its
// q = lane&15 spread over the 4-lane group {l, l^16, l^32, l^48} (64 regs).
// Exact top-128 via MSB radix-select, softmax in registers, P -> LDS bf16,
// PV via mfma(P,V).
__global__ __launch_bounds__(256) void attn_k(
    const ushort* __restrict__ qhi_, const ushort* __restrict__ qlo_,
    const ushort* __restrict__ khi_, const ushort* __restrict__ klo_,
    const ushort* __restrict__ vv,
    const float* __restrict__ pe, const float* __restrict__ pvc,
    ushort* __restrict__ ao)
{
  extern __shared__ char smem[];
  ushort* Khi = (ushort*)(smem);            // [256][72] bf16
  ushort* Klo = (ushort*)(smem + 36864);    // [256][72]
  ushort* Vt  = (ushort*)(smem + 73728);    // [64][264] (V transposed: [hd][kpos])
  char*   Pw  = smem + 107520 + (threadIdx.x >> 6) * 8448;  // per-wave P [16][264] bf16

  int bh = blockIdx.x, b = bh >> 3, h = bh & 7;
  int tid = threadIdx.x, lane = tid & 63, w = tid >> 6;
  size_t base = (size_t)bh << 14;           // *16384

  for (int c = tid; c < 2048; c += 256){
    int row = c >> 3, off = (c & 7) << 3;
    *(uint4*)(&Khi[row*72 + off]) = *(const uint4*)(khi_ + base + row*64 + off);
    *(uint4*)(&Klo[row*72 + off]) = *(const uint4*)(klo_ + base + row*64 + off);
  }
  for (int c = tid; c < 2048; c += 256){
    int kp = c >> 3, d0 = (c & 7) << 3;
    uint4 xv = *(const uint4*)(vv + base + kp*64 + d0);
    const ushort* px = (const ushort*)&xv;
    #pragma unroll
    for (int j = 0; j < 8; j++) Vt[(d0 + j)*264 + kp] = px[j];
  }
  __syncthreads();

  float pvb = pvc[b] * 0.5f;

  for (int qt = 0; qt < 4; qt++){
    int qbase = w*64 + qt*16;
    int qg = qbase + (lane & 15);
    const ushort* qp1 = qhi_ + base + (size_t)qg*64 + ((lane>>4)<<3);
    const ushort* qp2 = qlo_ + base + (size_t)qg*64 + ((lane>>4)<<3);
    short8 qh0  = *(const short8*)(qp1);
    short8 qh1  = *(const short8*)(qp1 + 32);
    short8 ql0  = *(const short8*)(qp2);
    short8 ql1  = *(const short8*)(qp2 + 32);

    float4v acc[16];
    #pragma unroll
    for (int kt = 0; kt < 16; kt++){
      const ushort* kr1 = &Khi[(kt*16 + (lane&15))*72 + ((lane>>4)<<3)];
      const ushort* kr2 = &Klo[(kt*16 + (lane&15))*72 + ((lane>>4)<<3)];
      short8 kh0 = *(const short8*)(kr1);
      short8 kh1 = *(const short8*)(kr1 + 32);
      short8 kl0 = *(const short8*)(kr2);
      short8 kl1 = *(const short8*)(kr2 + 32);
      float4v a = {0.f,0.f,0.f,0.f};
      a = MFMA16(kh0, qh0, a);
      a = MFMA16(kh1, qh1, a);
      a = MFMA16(kh0, ql0, a);
      a = MFMA16(kh1, ql1, a);
      a = MFMA16(kl0, qh0, a);
      a = MFMA16(kl1, qh1, a);
      acc[kt] = a;
    }
    // scale + prior + price/vol cross-block bias (fp32, matches reference)
    bool qlow = (qg < 128);
    #pragma unroll
    for (int kt = 0; kt < 16; kt++){
      #pragma unroll
      for (int r = 0; r < 4; r++){
        int kpos = kt*16 + ((lane>>4)<<2) + r;
        acc[kt][r] = acc[kt][r]*0.125f + pe[qg*256 + kpos]
                   + ((qlow != (kpos < 128)) ? pvb : 0.0f);
      }
    }
    // exact 128th-largest per row (MSB radix-select on sortable-uint space;
    // counts via float compares against the mapped-back threshold).
    unsigned thr = 0u; int done = 0;
    for (int bit = 31; bit >= 0; --bit){
      if (__all(done)) break;
      unsigned cand = thr | (1u << bit);
      float tf = unsort_u(cand);
      int cnt = 0;
      #pragma unroll
      for (int kt = 0; kt < 16; kt++){
        #pragma unroll
        for (int r = 0; r < 4; r++)
          cnt += (acc[kt][r] >= tf) ? 1 : 0;
      }
      cnt += __shfl_xor(cnt, 16);
      cnt += __shfl_xor(cnt, 32);
      if (!done && cnt >= 128) thr = cand;
      if (!done && cnt == 128) done = 1;
    }
    float thrf = unsort_u(thr);
    // softmax over kept (row max is always kept)
    float m = -1e30f;
    #pragma unroll
    for (int kt = 0; kt < 16; kt++)
      m = fmaxf(m, fmaxf(fmaxf(acc[kt][0], acc[kt][1]), fmaxf(acc[kt][2], acc[kt][3])));
    m = fmaxf(m, __shfl_xor(m, 16));
    m = fmaxf(m, __shfl_xor(m, 32));
    float sum = 0.0f;
    #pragma unroll
    for (int kt = 0; kt < 16; kt++){
      #pragma unroll
      for (int r = 0; r < 4; r++){
        float e = (acc[kt][r] >= thrf) ? __expf(acc[kt][r] - m) : 0.0f;
        acc[kt][r] = e;
        sum += e;
      }
    }
    sum += __shfl_xor(sum, 16);
    sum += __shfl_xor(sum, 32);
    float inv = 1.0f / sum;
    // write normalized P (bf16) to per-wave LDS: P[q=lane&15][kpos]
    #pragma unroll
    for (int kt = 0; kt < 16; kt++){
      unsigned lo32 = (unsigned)f2bf(acc[kt][0]*inv) | ((unsigned)f2bf(acc[kt][1]*inv) << 16);
      unsigned hi32 = (unsigned)f2bf(acc[kt][2]*inv) | ((unsigned)f2bf(acc[kt][3]*inv) << 16);
      uint2 pk; pk.x = lo32; pk.y = hi32;
      *(uint2*)(Pw + (lane&15)*528 + kt*32 + ((lane>>4)<<3)) = pk;
    }
    // PV: out[q][hd] = sum_k P[q][k] * V[k][hd]
    #pragma unroll
    for (int ht = 0; ht < 4; ht++){
      float4v oa = {0.f,0.f,0.f,0.f};
      #pragma unroll
      for (int kb = 0; kb < 8; kb++){
        short8 pf = *(const short8*)(Pw + (lane&15)*528 + kb*64 + ((lane>>4)<<4));
        short8 vf = *(const short8*)(&Vt[(ht*16 + (lane&15))*264 + kb*32 + ((lane>>4)<<3)]);
        oa = MFMA16(pf, vf, oa);
      }
      #pragma unroll
      for (int r = 0; r < 4; r++){
        int qo = qbase + ((lane>>4)<<2) + r;
        ao[((size_t)(b*256 + qo) << 9) + (h<<6) + (ht<<4) + (lane&15)] = f2bf(oa[r]);
      }
    }
  }
}

// ---------------------------------------------------------------------------
extern "C" void kernel_launch(void* const* d_in, const int* in_sizes, int n_in,
                              void* d_out, int out_size, void* d_ws, size_t ws_size,
                              hipStream_t stream)
{
  const float* x     = (const float*)d_in[0];
  const float* Wq    = (const float*)d_in[1];
  const float* bq    = (const float*)d_in[2];
  const float* Wk    = (const float*)d_in[3];
  const float* bk    = (const float*)d_in[4];
  const float* Wv    = (const float*)d_in[5];
  const float* bv    = (const float*)d_in[6];
  const float* Wo    = (const float*)d_in[7];
  const float* bo    = (const float*)d_in[8];
  const float* prior = (const float*)d_in[9];
  const float* fimp  = (const float*)d_in[10];
  const float* W1    = (const float*)d_in[11];
  const float* b1    = (const float*)d_in[12];
  const float* W2    = (const float*)d_in[13];
  const float* b2    = (const float*)d_in[14];

  char* ws = (char*)d_ws;
  ushort* xhi  = (ushort*)(ws + 0);            // 16.78 MB
  ushort* xlo  = (ushort*)(ws + 16777216);
  ushort* qhi  = (ushort*)(ws + 33554432);
  ushort* qlo  = (ushort*)(ws + 50331648);
  ushort* khi  = (ushort*)(ws + 67108864);
  ushort* klo  = (ushort*)(ws + 83886080);
  ushort* vb   = (ushort*)(ws + 100663296);
  ushort* Wthi = (ushort*)(ws + 117440512);
  ushort* Wtlo = (ushort*)(ws + 119013376);
  ushort* Wot  = (ushort*)(ws + 120061952);
  float*  fb   = (float*) (ws + 120586240);
  float*  comb = (float*) (ws + 120592384);
  float*  pvc  = (float*) (ws + 120854528);
  float*  pe   = (float*) (ws + 120854784);
  ushort* ao   = xhi;   // alias: xhi dead after the projection GEMMs

  (void)hipFuncSetAttribute((const void*)attn_k,
      hipFuncAttributeMaxDynamicSharedMemorySize, 141312);

  cvt_x_k <<<4096, 256, 0, stream>>>(x, xhi, xlo);
  cvt_w_k <<<2049, 256, 0, stream>>>(Wq, Wk, Wv, Wo, bq, bk, bv, Wthi, Wtlo, Wot, fb);
  prior_k <<<256, 256, 0, stream>>>(prior, fimp, pe);
  pv_mean_k<<<64, 256, 0, stream>>>(x, comb);
  pv_mlp_k <<<64, 256, 0, stream>>>(comb, W1, b1, W2, b2, pvc);
  gemm_qk <<<dim3(8,128), 256, 0, stream>>>(xhi, xlo, Wthi, Wtlo, fb, qhi, qlo, khi, klo);
  gemm_pl<0><<<dim3(4,128), 256, 0, stream>>>(xhi, Wthi + (size_t)1024*512, fb + 1024, vb);
  attn_k  <<<512, 256, 141312, stream>>>(qhi, qlo, khi, klo, vb, pe, pvc, ao);
  gemm_pl<1><<<dim3(4,128), 256, 0, stream>>>(ao, Wot, bo, d_out);

  (void)in_sizes; (void)n_in; (void)out_size; (void)ws_size;
}